// Round 8
// baseline (258.929 us; speedup 1.0000x reference)
//
#include <hip/hip_runtime.h>
#include <stdint.h>

// ---------- types ----------
typedef unsigned short bf16u;                                    // raw bf16 bits
typedef unsigned int u32;
typedef __attribute__((ext_vector_type(8))) short s16x8;         // MFMA A/B frag (8 bf16)
typedef __attribute__((ext_vector_type(4))) float f32x4;         // 16x16 C/D frag
typedef __attribute__((ext_vector_type(16))) float f32x16;       // 32x32 C/D frag

// Q is pre-scaled by 1/sqrt(64) * log2(e) so softmax runs in exp2 domain.
#define QSCALE 0.18033688011112042f

static __device__ __forceinline__ bf16u f2bf(float f) {
    uint32_t u = __float_as_uint(f);
    uint32_t r = (u + 0x7FFFu + ((u >> 16) & 1u)) >> 16;         // RNE
    return (bf16u)r;
}
static __device__ __forceinline__ u32 pack2(float lo, float hi) {
    return (u32)f2bf(lo) | ((u32)f2bf(hi) << 16);
}
// D.lo = bf16(S0), D.hi = bf16(S1), RNE (T12 recipe, m240)
static __device__ __forceinline__ u32 cvtpk(float lo, float hi) {
    u32 r;
    asm("v_cvt_pk_bf16_f32 %0, %1, %2" : "=v"(r) : "v"(lo), "v"(hi));
    return r;
}

static __device__ __forceinline__ f32x4 mfma16(s16x8 a, s16x8 b, f32x4 c) {
    return __builtin_amdgcn_mfma_f32_16x16x32_bf16(a, b, c, 0, 0, 0);
}
static __device__ __forceinline__ f32x16 mfma32(s16x8 a, s16x8 b, f32x16 c) {
    return __builtin_amdgcn_mfma_f32_32x32x16_bf16(a, b, c, 0, 0, 0);
}

#define GLDS(gsrc, ldst)                                                        \
    __builtin_amdgcn_global_load_lds(                                           \
        (const __attribute__((address_space(1))) void*)(gsrc),                  \
        (__attribute__((address_space(3))) void*)(ldst), 16, 0, 0)

// ---------- fp32 -> bf16 convert ----------
__global__ __launch_bounds__(256) void cvt_f32_bf16_kernel(
    const float* __restrict__ in, bf16u* __restrict__ out, int n) {
    union Pack { bf16u h[8]; uint4 u; };
    for (int i = (blockIdx.x * 256 + threadIdx.x) * 8; i < n; i += gridDim.x * 256 * 8) {
        const float4 a = *(const float4*)(in + i);
        const float4 b = *(const float4*)(in + i + 4);
        Pack p;
        p.h[0] = f2bf(a.x); p.h[1] = f2bf(a.y); p.h[2] = f2bf(a.z); p.h[3] = f2bf(a.w);
        p.h[4] = f2bf(b.x); p.h[5] = f2bf(b.y); p.h[6] = f2bf(b.z); p.h[7] = f2bf(b.w);
        *(uint4*)(out + i) = p.u;
    }
}

// ---------- GEMM: C = A @ Bt^T (+bias). A:[M,K] bf16, Bt:[N,K] bf16 ----------
// MODE 0: fp32 out to Cf[M,N].
// MODE 1: scatter bf16: Q (pre-scaled by QSCALE), K -> [BH][2048][64];
//         V -> TRANSPOSED [BH][64][2048].
template <int MODE>
__global__ __launch_bounds__(256) void gemm_bt_kernel(
    const bf16u* __restrict__ A, const bf16u* __restrict__ Bt,
    const float* __restrict__ bias, float* __restrict__ Cf,
    bf16u* __restrict__ Qo, bf16u* __restrict__ Ko, bf16u* __restrict__ Vto,
    int M, int N, int K) {
    __shared__ bf16u As[128 * 32];   // [row][k], linear (global_load_lds dest)
    __shared__ bf16u Bs[128 * 32];
    const int tid  = threadIdx.x;
    const int wave = tid >> 6, lane = tid & 63;
    const int wr = wave >> 1, wc = wave & 1;
    const int ri = lane & 15, hi = lane >> 4;
    const int m0 = blockIdx.x * 128, n0 = blockIdx.y * 128;

    f32x4 acc[4][4];
#pragma unroll
    for (int i = 0; i < 4; ++i)
#pragma unroll
        for (int j = 0; j < 4; ++j) acc[i][j] = (f32x4){0.f, 0.f, 0.f, 0.f};

    for (int k0 = 0; k0 < K; k0 += 32) {
        __syncthreads();
#pragma unroll
        for (int it = 0; it < 2; ++it) {
            const int chunk = it * 4 + wave;          // 0..7, wave-uniform
            const int e = chunk * 512 + lane * 8;
            const int r = e >> 5, c = e & 31;
            GLDS(A  + (size_t)(m0 + r) * K + (k0 + c), As + chunk * 512);
            GLDS(Bt + (size_t)(n0 + r) * K + (k0 + c), Bs + chunk * 512);
        }
        __syncthreads();
        s16x8 af[4], bfr[4];
#pragma unroll
        for (int i = 0; i < 4; ++i) {
            af[i]  = *(const s16x8*)(As + (wr * 64 + i * 16 + ri) * 32 + hi * 8);
            bfr[i] = *(const s16x8*)(Bs + (wc * 64 + i * 16 + ri) * 32 + hi * 8);
        }
#pragma unroll
        for (int i = 0; i < 4; ++i)
#pragma unroll
            for (int j = 0; j < 4; ++j) acc[i][j] = mfma16(af[i], bfr[j], acc[i][j]);
    }

    // epilogue: D layout row=(lane>>4)*4+r, col=lane&15
#pragma unroll
    for (int i = 0; i < 4; ++i) {
#pragma unroll
        for (int j = 0; j < 4; ++j) {
#pragma unroll
            for (int r = 0; r < 4; ++r) {
                const int row = m0 + wr * 64 + i * 16 + hi * 4 + r;
                const int col = n0 + wc * 64 + j * 16 + ri;
                const float v = acc[i][j][r] + bias[col];
                if constexpr (MODE == 0) {
                    Cf[(size_t)row * N + col] = v;
                } else {
                    const int which = col >> 10, h = (col >> 6) & 15, d = col & 63;
                    const int b = row >> 11, t = row & 2047;
                    const int bh = b * 16 + h;
                    if (which == 2) {
                        Vto[(((size_t)bh) * 64 + d) * 2048 + t] = f2bf(v);
                    } else if (which == 0) {
                        Qo[(((size_t)bh) * 2048 + t) * 64 + d] = f2bf(v * QSCALE);
                    } else {
                        Ko[(((size_t)bh) * 2048 + t) * 64 + d] = f2bf(v);
                    }
                }
            }
        }
    }
}

// ---------- flash attention (swapped QK^T, 32x32 MFMA, KV-split) ----------
// Q,K: [BH][2048][64]; Vt: [BH][64][2048]; O: [B][2048][1024] bf16
// Block: 4 waves (256 thr) = 2 q-wave-groups x 2 KV-halves; 64 q-rows/block.
// Grid (2048/64, BH) = 1024 blocks -> 4 blocks/CU (4 independent barrier
// domains per CU; when one block stages, the other three compute).
// LDS rows padded to 72 elems: bank-quad = (row+slot)&7 -> conflict-free.
__global__ __launch_bounds__(256, 4) void attn_kernel(
    const bf16u* __restrict__ Q, const bf16u* __restrict__ K,
    const bf16u* __restrict__ Vt, bf16u* __restrict__ O) {
    __shared__ uint4 smem4[4 * 64 * 72 * 2 / 16];   // 36864 B: 4 staging tiles
    bf16u* Ks0 = (bf16u*)smem4;
    bf16u* Vs0 = Ks0 + 64 * 72;
    bf16u* Ks1 = Vs0 + 64 * 72;
    bf16u* Vs1 = Ks1 + 64 * 72;
    float* mrg = (float*)smem4;                     // overlay after loop: [2][64][35]

    const int tid = threadIdx.x, lane = tid & 63;
    const int wave = tid >> 6, wg = wave & 1, kvh = wave >> 1;
    const int ri = lane & 31, hi = lane >> 5;          // q-col / lane-half
    const int bh = blockIdx.y, b = bh >> 4, h = bh & 15;
    const int q0 = blockIdx.x * 64 + wg * 32;
    const bf16u* Qb = Q  + (size_t)bh * 2048 * 64;
    const bf16u* Kb = K  + (size_t)bh * 2048 * 64;
    const bf16u* Vb = Vt + (size_t)bh * 64 * 2048;

    // Q fragment (B-operand): lane holds row q0+ri, d = 16c + 8hi + e
    s16x8 qf[4];
#pragma unroll
    for (int c = 0; c < 4; ++c)
        qf[c] = *(const s16x8*)(Qb + (size_t)(q0 + ri) * 64 + c * 16 + hi * 8);

    const bf16u* Ksh = kvh ? Ks1 : Ks0;
    const bf16u* Vsh = kvh ? Vs1 : Vs0;

    f32x16 oacc[2];
#pragma unroll
    for (int r = 0; r < 16; ++r) { oacc[0][r] = 0.f; oacc[1][r] = 0.f; }
    float m = -1e30f, lsum = 0.f;

    for (int kt = 0; kt < 16; ++kt) {
        // load both halves' tiles to registers (issued before the barrier);
        // 256 threads -> 2 chunks per thread per tile
        uint4 k0[2], k1[2], v0[2], v1[2];
#pragma unroll
        for (int p = 0; p < 2; ++p) {
            const int chunkid = p * 256 + tid;       // 0..511
            const int row = chunkid >> 3, c = chunkid & 7;
            k0[p] = *(const uint4*)(Kb + (size_t)(kt * 64 + row) * 64 + c * 8);
            k1[p] = *(const uint4*)(Kb + (size_t)((kt + 16) * 64 + row) * 64 + c * 8);
            v0[p] = *(const uint4*)(Vb + (size_t)row * 2048 + kt * 64 + c * 8);
            v1[p] = *(const uint4*)(Vb + (size_t)row * 2048 + (kt + 16) * 64 + c * 8);
        }
        __syncthreads();  // previous tile's LDS reads complete
#pragma unroll
        for (int p = 0; p < 2; ++p) {
            const int chunkid = p * 256 + tid;
            const int row = chunkid >> 3, c = chunkid & 7;
            *(uint4*)(Ks0 + row * 72 + c * 8) = k0[p];
            *(uint4*)(Ks1 + row * 72 + c * 8) = k1[p];
            *(uint4*)(Vs0 + row * 72 + c * 8) = v0[p];
            *(uint4*)(Vs1 + row * 72 + c * 8) = v1[p];
        }
        __syncthreads();

        // S^T[k][q] = sum_d K[k][d] Q[q][d]  (2 tiles of 32k x 32q, 4 mfma each)
        f32x16 sa[2];
#pragma unroll
        for (int r = 0; r < 16; ++r) { sa[0][r] = 0.f; sa[1][r] = 0.f; }
#pragma unroll
        for (int kb2 = 0; kb2 < 2; ++kb2) {
            const int row = kb2 * 32 + ri;
#pragma unroll
            for (int c = 0; c < 4; ++c) {
                s16x8 kf = *(const s16x8*)(Ksh + row * 72 + (2 * c + hi) * 8);
                sa[kb2] = mfma32(kf, qf[c], sa[kb2]);
            }
        }

        // ---- online softmax in exp2 domain (lane owns q = q0+ri) ----
        float pmt[16];
#pragma unroll
        for (int r = 0; r < 16; ++r) pmt[r] = fmaxf(sa[0][r], sa[1][r]);
#pragma unroll
        for (int s = 8; s > 0; s >>= 1)
#pragma unroll
            for (int r = 0; r < s; ++r) pmt[r] = fmaxf(pmt[r], pmt[r + s]);
        const float pm = fmaxf(pmt[0], __shfl_xor(pmt[0], 32));

        // defer-max (T13): only rescale when the running max grows by > 8
        if (!__all(pm <= m + 8.f)) {
            const float mn = fmaxf(m, pm);
            const float al = __builtin_amdgcn_exp2f(m - mn);
            m = mn;
            lsum *= al;
#pragma unroll
            for (int r = 0; r < 16; ++r) { oacc[0][r] *= al; oacc[1][r] *= al; }
        }

        float rs0 = 0.f, rs1 = 0.f, rs2 = 0.f, rs3 = 0.f;
#pragma unroll
        for (int kb2 = 0; kb2 < 2; ++kb2)
#pragma unroll
            for (int r = 0; r < 16; ++r) {
                const float p = __builtin_amdgcn_exp2f(sa[kb2][r] - m);
                sa[kb2][r] = p;
                if ((r & 3) == 0) rs0 += p;
                else if ((r & 3) == 1) rs1 += p;
                else if ((r & 3) == 2) rs2 += p;
                else rs3 += p;
            }
        float rs = (rs0 + rs1) + (rs2 + rs3);
        rs += __shfl_xor(rs, 32);
        lsum += rs;

        // ---- pack P^T into B-frags: pb[k4] holds k = 16*k4 + 8*hi + e ----
        s16x8 pb[4];
#pragma unroll
        for (int blk = 0; blk < 2; ++blk) {
            u32 pk[4][2];
#pragma unroll
            for (int j = 0; j < 4; ++j) {
                pk[j][0] = cvtpk(sa[blk][4 * j + 0], sa[blk][4 * j + 1]);
                pk[j][1] = cvtpk(sa[blk][4 * j + 2], sa[blk][4 * j + 3]);
            }
#pragma unroll
            for (int halfq = 0; halfq < 2; ++halfq) {
                const int ja = 2 * halfq, jb = ja + 1;
                u32 keep0 = hi ? pk[jb][0] : pk[ja][0];
                u32 keep1 = hi ? pk[jb][1] : pk[ja][1];
                u32 send0 = hi ? pk[ja][0] : pk[jb][0];
                u32 send1 = hi ? pk[ja][1] : pk[jb][1];
                u32 recv0 = __shfl_xor(send0, 32);
                u32 recv1 = __shfl_xor(send1, 32);
                union { u32 w[4]; s16x8 v; } pu;
                pu.w[0] = hi ? recv0 : keep0;   // e0,e1
                pu.w[1] = hi ? recv1 : keep1;   // e2,e3
                pu.w[2] = hi ? keep0 : recv0;   // e4,e5
                pu.w[3] = hi ? keep1 : recv1;   // e6,e7
                pb[blk * 2 + halfq] = pu.v;
            }
        }

        // ---- O^T[d][q] += sum_k V^T[d][k] P^T[k][q] ----
#pragma unroll
        for (int dt = 0; dt < 2; ++dt) {
            const int row = dt * 32 + ri;
#pragma unroll
            for (int k4 = 0; k4 < 4; ++k4) {
                s16x8 vf = *(const s16x8*)(Vsh + row * 72 + (2 * k4 + hi) * 8);
                oacc[dt] = mfma32(vf, pb[k4], oacc[dt]);
            }
        }
    }

    // ---- flash merge of the two KV halves (overlay on staging LDS) ----
    __syncthreads();  // all staging reads done before overlay writes
    if (kvh) {
        float* p = mrg + (wg * 64 + lane) * 35;
        p[0] = m; p[1] = lsum;
#pragma unroll
        for (int r = 0; r < 16; ++r) { p[2 + r] = oacc[0][r]; p[18 + r] = oacc[1][r]; }
    }
    __syncthreads();
    if (!kvh) {
        const float* p = mrg + (wg * 64 + lane) * 35;
        const float m1 = p[0], l1 = p[1];
        const float mn = fmaxf(m, m1);
        const float a0 = __builtin_amdgcn_exp2f(m - mn);
        const float a1 = __builtin_amdgcn_exp2f(m1 - mn);
        const float inv = 1.f / (lsum * a0 + l1 * a1);
        const int t = q0 + ri;
        bf16u* Ob = O + ((size_t)b * 2048 + t) * 1024 + h * 64;
#pragma unroll
        for (int dt = 0; dt < 2; ++dt)
#pragma unroll
            for (int j = 0; j < 4; ++j) {
                const int d0 = dt * 32 + j * 8 + hi * 4;
                const float e0 = (oacc[dt][4 * j + 0] * a0 + p[2 + dt * 16 + 4 * j + 0] * a1) * inv;
                const float e1 = (oacc[dt][4 * j + 1] * a0 + p[2 + dt * 16 + 4 * j + 1] * a1) * inv;
                const float e2 = (oacc[dt][4 * j + 2] * a0 + p[2 + dt * 16 + 4 * j + 2] * a1) * inv;
                const float e3 = (oacc[dt][4 * j + 3] * a0 + p[2 + dt * 16 + 4 * j + 3] * a1) * inv;
                uint2 wv; wv.x = pack2(e0, e1); wv.y = pack2(e2, e3);
                *(uint2*)(Ob + d0) = wv;
            }
    }
}

// ---------- launch ----------
extern "C" void kernel_launch(void* const* d_in, const int* in_sizes, int n_in,
                              void* d_out, int out_size, void* d_ws, size_t ws_size,
                              hipStream_t stream) {
    const float* x     = (const float*)d_in[0];
    const float* w_in  = (const float*)d_in[1];
    const float* b_in  = (const float*)d_in[2];
    const float* w_out = (const float*)d_in[3];
    const float* b_out = (const float*)d_in[4];
    float* out = (float*)d_out;

    char* ws = (char*)d_ws;
    bf16u* xb    = (bf16u*)(ws);                          // 8 MB  (reused as attnb)
    bf16u* wqkvb = (bf16u*)(ws + 8388608);                // 6 MB
    bf16u* woutb = (bf16u*)(ws + 14680064);               // 2 MB
    bf16u* qb    = (bf16u*)(ws + 16777216);               // 8 MB
    bf16u* kb    = (bf16u*)(ws + 25165824);               // 8 MB
    bf16u* vtb   = (bf16u*)(ws + 33554432);               // 8 MB (V stored transposed)
    bf16u* attnb = xb;  // x is dead after the QKV GEMM

    cvt_f32_bf16_kernel<<<2048, 256, 0, stream>>>(x, xb, 4096 * 1024);
    cvt_f32_bf16_kernel<<<1536, 256, 0, stream>>>(w_in, wqkvb, 3072 * 1024);
    cvt_f32_bf16_kernel<<<512, 256, 0, stream>>>(w_out, woutb, 1024 * 1024);

    gemm_bt_kernel<1><<<dim3(32, 24), 256, 0, stream>>>(
        xb, wqkvb, b_in, nullptr, qb, kb, vtb, 4096, 3072, 1024);

    attn_kernel<<<dim3(32, 32), 256, 0, stream>>>(qb, kb, vtb, attnb);

    gemm_bt_kernel<0><<<dim3(32, 8), 256, 0, stream>>>(
        attnb, woutb, b_out, out, nullptr, nullptr, nullptr, 4096, 1024, 1024);
}

// Round 9
// 136.541 us; speedup vs baseline: 1.8963x; 1.8963x over previous
//
#include <hip/hip_runtime.h>
#include <stdint.h>

// ---------- types ----------
typedef unsigned short bf16u;                                    // raw bf16 bits
typedef unsigned int u32;
typedef __attribute__((ext_vector_type(8))) short s16x8;         // MFMA A/B frag (8 bf16)
typedef __attribute__((ext_vector_type(4))) float f32x4;         // 16x16 C/D frag
typedef __attribute__((ext_vector_type(16))) float f32x16;       // 32x32 C/D frag
typedef __attribute__((ext_vector_type(2))) int i32x2;

// Q is pre-scaled by 1/sqrt(64) * log2(e) so softmax runs in exp2 domain.
#define QSCALE 0.18033688011112042f

static __device__ __forceinline__ bf16u f2bf(float f) {
    uint32_t u = __float_as_uint(f);
    uint32_t r = (u + 0x7FFFu + ((u >> 16) & 1u)) >> 16;         // RNE
    return (bf16u)r;
}
static __device__ __forceinline__ u32 pack2(float lo, float hi) {
    return (u32)f2bf(lo) | ((u32)f2bf(hi) << 16);
}
// D.lo = bf16(S0), D.hi = bf16(S1), RNE (T12 recipe, m240)
static __device__ __forceinline__ u32 cvtpk(float lo, float hi) {
    u32 r;
    asm("v_cvt_pk_bf16_f32 %0, %1, %2" : "=v"(r) : "v"(lo), "v"(hi));
    return r;
}
// ret.x = X': lanes<32 keep X, lanes>=32 get Y's low half;
// ret.y = Y': lanes<32 get X's high half, lanes>=32 keep Y.
static __device__ __forceinline__ i32x2 plswap(u32 x, u32 y) {
    return __builtin_amdgcn_permlane32_swap((int)x, (int)y, false, false);
}

static __device__ __forceinline__ f32x4 mfma16(s16x8 a, s16x8 b, f32x4 c) {
    return __builtin_amdgcn_mfma_f32_16x16x32_bf16(a, b, c, 0, 0, 0);
}
static __device__ __forceinline__ f32x16 mfma32(s16x8 a, s16x8 b, f32x16 c) {
    return __builtin_amdgcn_mfma_f32_32x32x16_bf16(a, b, c, 0, 0, 0);
}

#define GLDS(gsrc, ldst)                                                        \
    __builtin_amdgcn_global_load_lds(                                           \
        (const __attribute__((address_space(1))) void*)(gsrc),                  \
        (__attribute__((address_space(3))) void*)(ldst), 16, 0, 0)

// ---------- fp32 -> bf16 convert ----------
__global__ __launch_bounds__(256) void cvt_f32_bf16_kernel(
    const float* __restrict__ in, bf16u* __restrict__ out, int n) {
    union Pack { bf16u h[8]; uint4 u; };
    for (int i = (blockIdx.x * 256 + threadIdx.x) * 8; i < n; i += gridDim.x * 256 * 8) {
        const float4 a = *(const float4*)(in + i);
        const float4 b = *(const float4*)(in + i + 4);
        Pack p;
        p.h[0] = f2bf(a.x); p.h[1] = f2bf(a.y); p.h[2] = f2bf(a.z); p.h[3] = f2bf(a.w);
        p.h[4] = f2bf(b.x); p.h[5] = f2bf(b.y); p.h[6] = f2bf(b.z); p.h[7] = f2bf(b.w);
        *(uint4*)(out + i) = p.u;
    }
}

// ---------- GEMM: C = A @ Bt^T (+bias). A:[M,K] bf16, Bt:[N,K] bf16 ----------
// MODE 0: fp32 out to Cf[M,N].
// MODE 1: scatter bf16: Q (pre-scaled by QSCALE), K -> [BH][2048][64];
//         V -> TRANSPOSED [BH][64][2048].
template <int MODE>
__global__ __launch_bounds__(256) void gemm_bt_kernel(
    const bf16u* __restrict__ A, const bf16u* __restrict__ Bt,
    const float* __restrict__ bias, float* __restrict__ Cf,
    bf16u* __restrict__ Qo, bf16u* __restrict__ Ko, bf16u* __restrict__ Vto,
    int M, int N, int K) {
    __shared__ bf16u As[128 * 32];   // [row][k], linear (global_load_lds dest)
    __shared__ bf16u Bs[128 * 32];
    const int tid  = threadIdx.x;
    const int wave = tid >> 6, lane = tid & 63;
    const int wr = wave >> 1, wc = wave & 1;
    const int ri = lane & 15, hi = lane >> 4;
    const int m0 = blockIdx.x * 128, n0 = blockIdx.y * 128;

    f32x4 acc[4][4];
#pragma unroll
    for (int i = 0; i < 4; ++i)
#pragma unroll
        for (int j = 0; j < 4; ++j) acc[i][j] = (f32x4){0.f, 0.f, 0.f, 0.f};

    for (int k0 = 0; k0 < K; k0 += 32) {
        __syncthreads();
#pragma unroll
        for (int it = 0; it < 2; ++it) {
            const int chunk = it * 4 + wave;          // 0..7, wave-uniform
            const int e = chunk * 512 + lane * 8;
            const int r = e >> 5, c = e & 31;
            GLDS(A  + (size_t)(m0 + r) * K + (k0 + c), As + chunk * 512);
            GLDS(Bt + (size_t)(n0 + r) * K + (k0 + c), Bs + chunk * 512);
        }
        __syncthreads();
        s16x8 af[4], bfr[4];
#pragma unroll
        for (int i = 0; i < 4; ++i) {
            af[i]  = *(const s16x8*)(As + (wr * 64 + i * 16 + ri) * 32 + hi * 8);
            bfr[i] = *(const s16x8*)(Bs + (wc * 64 + i * 16 + ri) * 32 + hi * 8);
        }
#pragma unroll
        for (int i = 0; i < 4; ++i)
#pragma unroll
            for (int j = 0; j < 4; ++j) acc[i][j] = mfma16(af[i], bfr[j], acc[i][j]);
    }

    // epilogue: D layout row=(lane>>4)*4+r, col=lane&15
#pragma unroll
    for (int i = 0; i < 4; ++i) {
#pragma unroll
        for (int j = 0; j < 4; ++j) {
#pragma unroll
            for (int r = 0; r < 4; ++r) {
                const int row = m0 + wr * 64 + i * 16 + hi * 4 + r;
                const int col = n0 + wc * 64 + j * 16 + ri;
                const float v = acc[i][j][r] + bias[col];
                if constexpr (MODE == 0) {
                    Cf[(size_t)row * N + col] = v;
                } else {
                    const int which = col >> 10, h = (col >> 6) & 15, d = col & 63;
                    const int b = row >> 11, t = row & 2047;
                    const int bh = b * 16 + h;
                    if (which == 2) {
                        Vto[(((size_t)bh) * 64 + d) * 2048 + t] = f2bf(v);
                    } else if (which == 0) {
                        Qo[(((size_t)bh) * 2048 + t) * 64 + d] = f2bf(v * QSCALE);
                    } else {
                        Ko[(((size_t)bh) * 2048 + t) * 64 + d] = f2bf(v);
                    }
                }
            }
        }
    }
}

// ---------- flash attention (swapped QK^T, 32x32 MFMA, KV-split) ----------
// Q,K: [BH][2048][64]; Vt: [BH][64][2048]; O: [B][2048][1024] bf16
// Block: 8 waves (512 thr). Wave-groups {0-3}/{4-7}: same 128 q-rows,
// disjoint KV halves (tiles 0-15 / 16-31); flash-merge at the end.
// LDS rows padded to 72 elems: bank-quad = (row+slot)&7 -> conflict-free.
__global__ __launch_bounds__(512) void attn_kernel(
    const bf16u* __restrict__ Q, const bf16u* __restrict__ K,
    const bf16u* __restrict__ Vt, bf16u* __restrict__ O) {
    __shared__ uint4 smem4[4 * 64 * 72 * 2 / 16];   // 36864 B: 4 staging tiles
    bf16u* Ks0 = (bf16u*)smem4;
    bf16u* Vs0 = Ks0 + 64 * 72;
    bf16u* Ks1 = Vs0 + 64 * 72;
    bf16u* Vs1 = Ks1 + 64 * 72;
    float* mrg = (float*)smem4;                     // overlay after loop: [4][64][35]

    const int tid = threadIdx.x, lane = tid & 63;
    const int wave = tid >> 6, wg = wave & 3, kvh = wave >> 2;
    const int ri = lane & 31, hi = lane >> 5;          // q-col / lane-half
    const int bh = blockIdx.y, b = bh >> 4, h = bh & 15;
    const int q0 = blockIdx.x * 128 + wg * 32;
    const bf16u* Qb = Q  + (size_t)bh * 2048 * 64;
    const bf16u* Kb = K  + (size_t)bh * 2048 * 64;
    const bf16u* Vb = Vt + (size_t)bh * 64 * 2048;

    // Q fragment (B-operand): lane holds row q0+ri, d = 16c + 8hi + e
    s16x8 qf[4];
#pragma unroll
    for (int c = 0; c < 4; ++c)
        qf[c] = *(const s16x8*)(Qb + (size_t)(q0 + ri) * 64 + c * 16 + hi * 8);

    const bf16u* Ksh = kvh ? Ks1 : Ks0;
    const bf16u* Vsh = kvh ? Vs1 : Vs0;

    f32x16 oacc[2];
#pragma unroll
    for (int r = 0; r < 16; ++r) { oacc[0][r] = 0.f; oacc[1][r] = 0.f; }
    float m = -1e30f, lsum = 0.f;

    const int srow = tid >> 3, sc = tid & 7;           // 512 thr: one 16B chunk/tile
    for (int kt = 0; kt < 16; ++kt) {
        // load both halves' tiles to registers (issued before the barrier)
        const uint4 k0 = *(const uint4*)(Kb + (size_t)(kt * 64 + srow) * 64 + sc * 8);
        const uint4 k1 = *(const uint4*)(Kb + (size_t)((kt + 16) * 64 + srow) * 64 + sc * 8);
        const uint4 v0 = *(const uint4*)(Vb + (size_t)srow * 2048 + kt * 64 + sc * 8);
        const uint4 v1 = *(const uint4*)(Vb + (size_t)srow * 2048 + (kt + 16) * 64 + sc * 8);
        __syncthreads();  // previous tile's LDS reads complete
        *(uint4*)(Ks0 + srow * 72 + sc * 8) = k0;
        *(uint4*)(Ks1 + srow * 72 + sc * 8) = k1;
        *(uint4*)(Vs0 + srow * 72 + sc * 8) = v0;
        *(uint4*)(Vs1 + srow * 72 + sc * 8) = v1;
        __syncthreads();

        // S^T[k][q] = sum_d K[k][d] Q[q][d]  (2 tiles of 32k x 32q, 4 mfma each)
        f32x16 sa[2];
#pragma unroll
        for (int r = 0; r < 16; ++r) { sa[0][r] = 0.f; sa[1][r] = 0.f; }
#pragma unroll
        for (int kb2 = 0; kb2 < 2; ++kb2) {
            const int row = kb2 * 32 + ri;
#pragma unroll
            for (int c = 0; c < 4; ++c) {
                s16x8 kf = *(const s16x8*)(Ksh + row * 72 + (2 * c + hi) * 8);
                sa[kb2] = mfma32(kf, qf[c], sa[kb2]);
            }
        }

        // ---- online softmax in exp2 domain (lane owns q = q0+ri) ----
        float pmt[16];
#pragma unroll
        for (int r = 0; r < 16; ++r) pmt[r] = fmaxf(sa[0][r], sa[1][r]);
#pragma unroll
        for (int s = 8; s > 0; s >>= 1)
#pragma unroll
            for (int r = 0; r < s; ++r) pmt[r] = fmaxf(pmt[r], pmt[r + s]);
        const float pm = fmaxf(pmt[0], __shfl_xor(pmt[0], 32));

        // defer-max (T13): only rescale when the running max grows by > 8
        if (!__all(pm <= m + 8.f)) {
            const float mn = fmaxf(m, pm);
            const float al = __builtin_amdgcn_exp2f(m - mn);
            m = mn;
            lsum *= al;
#pragma unroll
            for (int r = 0; r < 16; ++r) { oacc[0][r] *= al; oacc[1][r] *= al; }
        }

        float rs0 = 0.f, rs1 = 0.f, rs2 = 0.f, rs3 = 0.f;
#pragma unroll
        for (int kb2 = 0; kb2 < 2; ++kb2)
#pragma unroll
            for (int r = 0; r < 16; ++r) {
                const float p = __builtin_amdgcn_exp2f(sa[kb2][r] - m);
                sa[kb2][r] = p;
                if ((r & 3) == 0) rs0 += p;
                else if ((r & 3) == 1) rs1 += p;
                else if ((r & 3) == 2) rs2 += p;
                else rs3 += p;
            }
        float rs = (rs0 + rs1) + (rs2 + rs3);
        rs += __shfl_xor(rs, 32);
        lsum += rs;

        // ---- pack P^T into B-frags: pb[k4] holds k = 16*k4 + 8*hi + e ----
        // 16 cvt_pk + 8 permlane32_swap (T12):
        // s = plswap(pk[ja][w], pk[jb][w]) -> word[w] = s.x, word[2+w] = s.y
        s16x8 pb[4];
#pragma unroll
        for (int blk = 0; blk < 2; ++blk) {
            u32 pk[4][2];
#pragma unroll
            for (int j = 0; j < 4; ++j) {
                pk[j][0] = cvtpk(sa[blk][4 * j + 0], sa[blk][4 * j + 1]);
                pk[j][1] = cvtpk(sa[blk][4 * j + 2], sa[blk][4 * j + 3]);
            }
#pragma unroll
            for (int halfq = 0; halfq < 2; ++halfq) {
                const int ja = 2 * halfq, jb = ja + 1;
                const i32x2 s0 = plswap(pk[ja][0], pk[jb][0]);
                const i32x2 s1 = plswap(pk[ja][1], pk[jb][1]);
                union { u32 w[4]; s16x8 v; } pu;
                pu.w[0] = (u32)s0.x;   // e0,e1
                pu.w[1] = (u32)s1.x;   // e2,e3
                pu.w[2] = (u32)s0.y;   // e4,e5
                pu.w[3] = (u32)s1.y;   // e6,e7
                pb[blk * 2 + halfq] = pu.v;
            }
        }

        // ---- O^T[d][q] += sum_k V^T[d][k] P^T[k][q] ----
#pragma unroll
        for (int dt = 0; dt < 2; ++dt) {
            const int row = dt * 32 + ri;
#pragma unroll
            for (int k4 = 0; k4 < 4; ++k4) {
                s16x8 vf = *(const s16x8*)(Vsh + row * 72 + (2 * k4 + hi) * 8);
                oacc[dt] = mfma32(vf, pb[k4], oacc[dt]);
            }
        }
    }

    // ---- flash merge of the two KV halves (overlay on staging LDS) ----
    __syncthreads();  // all staging reads done before overlay writes
    if (kvh) {
        float* p = mrg + (wg * 64 + lane) * 35;
        p[0] = m; p[1] = lsum;
#pragma unroll
        for (int r = 0; r < 16; ++r) { p[2 + r] = oacc[0][r]; p[18 + r] = oacc[1][r]; }
    }
    __syncthreads();
    if (!kvh) {
        const float* p = mrg + (wg * 64 + lane) * 35;
        const float m1 = p[0], l1 = p[1];
        const float mn = fmaxf(m, m1);
        const float a0 = __builtin_amdgcn_exp2f(m - mn);
        const float a1 = __builtin_amdgcn_exp2f(m1 - mn);
        const float inv = 1.f / (lsum * a0 + l1 * a1);
        const int t = q0 + ri;
        bf16u* Ob = O + ((size_t)b * 2048 + t) * 1024 + h * 64;
#pragma unroll
        for (int dt = 0; dt < 2; ++dt)
#pragma unroll
            for (int j = 0; j < 4; ++j) {
                const int d0 = dt * 32 + j * 8 + hi * 4;
                const float e0 = (oacc[dt][4 * j + 0] * a0 + p[2 + dt * 16 + 4 * j + 0] * a1) * inv;
                const float e1 = (oacc[dt][4 * j + 1] * a0 + p[2 + dt * 16 + 4 * j + 1] * a1) * inv;
                const float e2 = (oacc[dt][4 * j + 2] * a0 + p[2 + dt * 16 + 4 * j + 2] * a1) * inv;
                const float e3 = (oacc[dt][4 * j + 3] * a0 + p[2 + dt * 16 + 4 * j + 3] * a1) * inv;
                uint2 wv; wv.x = pack2(e0, e1); wv.y = pack2(e2, e3);
                *(uint2*)(Ob + d0) = wv;
            }
    }
}

// ---------- launch ----------
extern "C" void kernel_launch(void* const* d_in, const int* in_sizes, int n_in,
                              void* d_out, int out_size, void* d_ws, size_t ws_size,
                              hipStream_t stream) {
    const float* x     = (const float*)d_in[0];
    const float* w_in  = (const float*)d_in[1];
    const float* b_in  = (const float*)d_in[2];
    const float* w_out = (const float*)d_in[3];
    const float* b_out = (const float*)d_in[4];
    float* out = (float*)d_out;

    char* ws = (char*)d_ws;
    bf16u* xb    = (bf16u*)(ws);                          // 8 MB  (reused as attnb)
    bf16u* wqkvb = (bf16u*)(ws + 8388608);                // 6 MB
    bf16u* woutb = (bf16u*)(ws + 14680064);               // 2 MB
    bf16u* qb    = (bf16u*)(ws + 16777216);               // 8 MB
    bf16u* kb    = (bf16u*)(ws + 25165824);               // 8 MB
    bf16u* vtb   = (bf16u*)(ws + 33554432);               // 8 MB (V stored transposed)
    bf16u* attnb = xb;  // x is dead after the QKV GEMM

    cvt_f32_bf16_kernel<<<2048, 256, 0, stream>>>(x, xb, 4096 * 1024);
    cvt_f32_bf16_kernel<<<1536, 256, 0, stream>>>(w_in, wqkvb, 3072 * 1024);
    cvt_f32_bf16_kernel<<<512, 256, 0, stream>>>(w_out, woutb, 1024 * 1024);

    gemm_bt_kernel<1><<<dim3(32, 24), 256, 0, stream>>>(
        xb, wqkvb, b_in, nullptr, qb, kb, vtb, 4096, 3072, 1024);

    attn_kernel<<<dim3(16, 32), 512, 0, stream>>>(qb, kb, vtb, attnb);

    gemm_bt_kernel<0><<<dim3(32, 8), 256, 0, stream>>>(
        attnb, woutb, b_out, out, nullptr, nullptr, nullptr, 4096, 1024, 1024);
}

// Round 10
// 133.798 us; speedup vs baseline: 1.9352x; 1.0205x over previous
//
#include <hip/hip_runtime.h>
#include <stdint.h>

// ---------- types ----------
typedef unsigned short bf16u;                                    // raw bf16 bits
typedef unsigned int u32;
typedef __attribute__((ext_vector_type(8))) short s16x8;         // MFMA A/B frag (8 bf16)
typedef __attribute__((ext_vector_type(4))) float f32x4;         // 16x16 C/D frag
typedef __attribute__((ext_vector_type(16))) float f32x16;       // 32x32 C/D frag
typedef __attribute__((ext_vector_type(2))) int i32x2;

// Q is pre-scaled by 1/sqrt(64) * log2(e) so softmax runs in exp2 domain.
#define QSCALE 0.18033688011112042f

static __device__ __forceinline__ bf16u f2bf(float f) {
    uint32_t u = __float_as_uint(f);
    uint32_t r = (u + 0x7FFFu + ((u >> 16) & 1u)) >> 16;         // RNE
    return (bf16u)r;
}
static __device__ __forceinline__ u32 pack2(float lo, float hi) {
    return (u32)f2bf(lo) | ((u32)f2bf(hi) << 16);
}
// D.lo = bf16(S0), D.hi = bf16(S1), RNE (T12 recipe, m240)
static __device__ __forceinline__ u32 cvtpk(float lo, float hi) {
    u32 r;
    asm("v_cvt_pk_bf16_f32 %0, %1, %2" : "=v"(r) : "v"(lo), "v"(hi));
    return r;
}
// ret.x = X': lanes<32 keep X, lanes>=32 get Y's low half;
// ret.y = Y': lanes<32 get X's high half, lanes>=32 keep Y.
static __device__ __forceinline__ i32x2 plswap(u32 x, u32 y) {
    return __builtin_amdgcn_permlane32_swap((int)x, (int)y, false, false);
}

static __device__ __forceinline__ f32x4 mfma16(s16x8 a, s16x8 b, f32x4 c) {
    return __builtin_amdgcn_mfma_f32_16x16x32_bf16(a, b, c, 0, 0, 0);
}
static __device__ __forceinline__ f32x16 mfma32(s16x8 a, s16x8 b, f32x16 c) {
    return __builtin_amdgcn_mfma_f32_32x32x16_bf16(a, b, c, 0, 0, 0);
}

#define GLDS(gsrc, ldst)                                                        \
    __builtin_amdgcn_global_load_lds(                                           \
        (const __attribute__((address_space(1))) void*)(gsrc),                  \
        (__attribute__((address_space(3))) void*)(ldst), 16, 0, 0)

// ---------- fp32 -> bf16 convert (three arrays fused, one launch) ----------
__global__ __launch_bounds__(256) void cvt3_f32_bf16_kernel(
    const float* __restrict__ in0, bf16u* __restrict__ out0, int n0,
    const float* __restrict__ in1, bf16u* __restrict__ out1, int n1,
    const float* __restrict__ in2, bf16u* __restrict__ out2, int n2) {
    union Pack { bf16u h[8]; uint4 u; };
    const int step = gridDim.x * 256 * 8;
#define CVT_LOOP(inp, outp, n)                                                  \
    for (int i = (blockIdx.x * 256 + threadIdx.x) * 8; i < (n); i += step) {    \
        const float4 a = *(const float4*)((inp) + i);                           \
        const float4 b = *(const float4*)((inp) + i + 4);                       \
        Pack p;                                                                 \
        p.h[0] = f2bf(a.x); p.h[1] = f2bf(a.y); p.h[2] = f2bf(a.z);             \
        p.h[3] = f2bf(a.w); p.h[4] = f2bf(b.x); p.h[5] = f2bf(b.y);             \
        p.h[6] = f2bf(b.z); p.h[7] = f2bf(b.w);                                 \
        *(uint4*)((outp) + i) = p.u;                                            \
    }
    CVT_LOOP(in0, out0, n0)
    CVT_LOOP(in1, out1, n1)
    CVT_LOOP(in2, out2, n2)
#undef CVT_LOOP
}

// ---------- GEMM: C = A @ Bt^T (+bias). A:[M,K] bf16, Bt:[N,K] bf16 ----------
// MODE 0: fp32 out to Cf[M,N].
// MODE 1: scatter bf16: Q (pre-scaled by QSCALE), K -> [BH][2048][64];
//         V -> TRANSPOSED [BH][64][2048].
// XCD swizzle (T1): each XCD owns a RECTM x RECTN rectangle of 128^2 tiles so
// its A/B panels stay resident in the per-XCD L2. Requires nwg % 8 == 0.
template <int MODE, int RECTM, int RECTN>
__global__ __launch_bounds__(256) void gemm_bt_kernel(
    const bf16u* __restrict__ A, const bf16u* __restrict__ Bt,
    const float* __restrict__ bias, float* __restrict__ Cf,
    bf16u* __restrict__ Qo, bf16u* __restrict__ Ko, bf16u* __restrict__ Vto,
    int M, int N, int K) {
    __shared__ bf16u As[128 * 32];   // [row][k], linear (global_load_lds dest)
    __shared__ bf16u Bs[128 * 32];
    const int tid  = threadIdx.x;
    const int wave = tid >> 6, lane = tid & 63;
    const int wr = wave >> 1, wc = wave & 1;
    const int ri = lane & 15, hi = lane >> 4;

    const int id  = blockIdx.x + blockIdx.y * gridDim.x;  // HW round-robins id%8
    const int xcd = id & 7, rr = id >> 3;                 // rr < RECTM*RECTN
    const int nrm = gridDim.x / RECTM;                    // rect columns in m
    const int m0 = ((xcd % nrm) * RECTM + (rr % RECTM)) * 128;
    const int n0 = ((xcd / nrm) * RECTN + (rr / RECTM)) * 128;

    f32x4 acc[4][4];
#pragma unroll
    for (int i = 0; i < 4; ++i)
#pragma unroll
        for (int j = 0; j < 4; ++j) acc[i][j] = (f32x4){0.f, 0.f, 0.f, 0.f};

    for (int k0 = 0; k0 < K; k0 += 32) {
        __syncthreads();
#pragma unroll
        for (int it = 0; it < 2; ++it) {
            const int chunk = it * 4 + wave;          // 0..7, wave-uniform
            const int e = chunk * 512 + lane * 8;
            const int r = e >> 5, c = e & 31;
            GLDS(A  + (size_t)(m0 + r) * K + (k0 + c), As + chunk * 512);
            GLDS(Bt + (size_t)(n0 + r) * K + (k0 + c), Bs + chunk * 512);
        }
        __syncthreads();
        s16x8 af[4], bfr[4];
#pragma unroll
        for (int i = 0; i < 4; ++i) {
            af[i]  = *(const s16x8*)(As + (wr * 64 + i * 16 + ri) * 32 + hi * 8);
            bfr[i] = *(const s16x8*)(Bs + (wc * 64 + i * 16 + ri) * 32 + hi * 8);
        }
#pragma unroll
        for (int i = 0; i < 4; ++i)
#pragma unroll
            for (int j = 0; j < 4; ++j) acc[i][j] = mfma16(af[i], bfr[j], acc[i][j]);
    }

    // epilogue: D layout row=(lane>>4)*4+r, col=lane&15
#pragma unroll
    for (int i = 0; i < 4; ++i) {
#pragma unroll
        for (int j = 0; j < 4; ++j) {
#pragma unroll
            for (int r = 0; r < 4; ++r) {
                const int row = m0 + wr * 64 + i * 16 + hi * 4 + r;
                const int col = n0 + wc * 64 + j * 16 + ri;
                const float v = acc[i][j][r] + bias[col];
                if constexpr (MODE == 0) {
                    Cf[(size_t)row * N + col] = v;
                } else {
                    const int which = col >> 10, h = (col >> 6) & 15, d = col & 63;
                    const int b = row >> 11, t = row & 2047;
                    const int bh = b * 16 + h;
                    if (which == 2) {
                        Vto[(((size_t)bh) * 64 + d) * 2048 + t] = f2bf(v);
                    } else if (which == 0) {
                        Qo[(((size_t)bh) * 2048 + t) * 64 + d] = f2bf(v * QSCALE);
                    } else {
                        Ko[(((size_t)bh) * 2048 + t) * 64 + d] = f2bf(v);
                    }
                }
            }
        }
    }
}

// ---------- flash attention (swapped QK^T, 32x32 MFMA, KV-split) ----------
// Q,K: [BH][2048][64]; Vt: [BH][64][2048]; O: [B][2048][1024] bf16
// Block: 8 waves (512 thr). Wave-groups {0-3}/{4-7}: same 128 q-rows,
// disjoint KV halves (tiles 0-15 / 16-31); flash-merge at the end.
// XCD swizzle: each XCD owns 4 complete bh groups (2 MB KV -> L2-resident).
// LDS rows padded to 72 elems: bank-quad = (row+slot)&7 -> conflict-free.
__global__ __launch_bounds__(512) void attn_kernel(
    const bf16u* __restrict__ Q, const bf16u* __restrict__ K,
    const bf16u* __restrict__ Vt, bf16u* __restrict__ O) {
    __shared__ uint4 smem4[4 * 64 * 72 * 2 / 16];   // 36864 B: 4 staging tiles
    bf16u* Ks0 = (bf16u*)smem4;
    bf16u* Vs0 = Ks0 + 64 * 72;
    bf16u* Ks1 = Vs0 + 64 * 72;
    bf16u* Vs1 = Ks1 + 64 * 72;
    float* mrg = (float*)smem4;                     // overlay after loop: [4][64][35]

    const int tid = threadIdx.x, lane = tid & 63;
    const int wave = tid >> 6, wg = wave & 3, kvh = wave >> 2;
    const int ri = lane & 31, hi = lane >> 5;          // q-col / lane-half

    const int id  = blockIdx.x + blockIdx.y * gridDim.x;  // gridDim.x = 16
    const int xcd = id & 7, rr = id >> 3;                 // rr < 64
    const int bh = xcd * 4 + (rr >> 4);                   // 4 bh groups per XCD
    const int bq = rr & 15;

    const int b = bh >> 4, h = bh & 15;
    const int q0 = bq * 128 + wg * 32;
    const bf16u* Qb = Q  + (size_t)bh * 2048 * 64;
    const bf16u* Kb = K  + (size_t)bh * 2048 * 64;
    const bf16u* Vb = Vt + (size_t)bh * 64 * 2048;

    // Q fragment (B-operand): lane holds row q0+ri, d = 16c + 8hi + e
    s16x8 qf[4];
#pragma unroll
    for (int c = 0; c < 4; ++c)
        qf[c] = *(const s16x8*)(Qb + (size_t)(q0 + ri) * 64 + c * 16 + hi * 8);

    const bf16u* Ksh = kvh ? Ks1 : Ks0;
    const bf16u* Vsh = kvh ? Vs1 : Vs0;

    f32x16 oacc[2];
#pragma unroll
    for (int r = 0; r < 16; ++r) { oacc[0][r] = 0.f; oacc[1][r] = 0.f; }
    float m = -1e30f, lsum = 0.f;

    const int srow = tid >> 3, sc = tid & 7;           // 512 thr: one 16B chunk/tile
    for (int kt = 0; kt < 16; ++kt) {
        // load both halves' tiles to registers (issued before the barrier)
        const uint4 k0 = *(const uint4*)(Kb + (size_t)(kt * 64 + srow) * 64 + sc * 8);
        const uint4 k1 = *(const uint4*)(Kb + (size_t)((kt + 16) * 64 + srow) * 64 + sc * 8);
        const uint4 v0 = *(const uint4*)(Vb + (size_t)srow * 2048 + kt * 64 + sc * 8);
        const uint4 v1 = *(const uint4*)(Vb + (size_t)srow * 2048 + (kt + 16) * 64 + sc * 8);
        __syncthreads();  // previous tile's LDS reads complete
        *(uint4*)(Ks0 + srow * 72 + sc * 8) = k0;
        *(uint4*)(Ks1 + srow * 72 + sc * 8) = k1;
        *(uint4*)(Vs0 + srow * 72 + sc * 8) = v0;
        *(uint4*)(Vs1 + srow * 72 + sc * 8) = v1;
        __syncthreads();

        // S^T[k][q] = sum_d K[k][d] Q[q][d]  (2 tiles of 32k x 32q, 4 mfma each)
        f32x16 sa[2];
#pragma unroll
        for (int r = 0; r < 16; ++r) { sa[0][r] = 0.f; sa[1][r] = 0.f; }
#pragma unroll
        for (int kb2 = 0; kb2 < 2; ++kb2) {
            const int row = kb2 * 32 + ri;
#pragma unroll
            for (int c = 0; c < 4; ++c) {
                s16x8 kf = *(const s16x8*)(Ksh + row * 72 + (2 * c + hi) * 8);
                sa[kb2] = mfma32(kf, qf[c], sa[kb2]);
            }
        }

        // ---- online softmax in exp2 domain (lane owns q = q0+ri) ----
        float pmt[16];
#pragma unroll
        for (int r = 0; r < 16; ++r) pmt[r] = fmaxf(sa[0][r], sa[1][r]);
#pragma unroll
        for (int s = 8; s > 0; s >>= 1)
#pragma unroll
            for (int r = 0; r < s; ++r) pmt[r] = fmaxf(pmt[r], pmt[r + s]);
        const float pm = fmaxf(pmt[0], __shfl_xor(pmt[0], 32));

        // defer-max (T13): only rescale when the running max grows by > 8
        if (!__all(pm <= m + 8.f)) {
            const float mn = fmaxf(m, pm);
            const float al = __builtin_amdgcn_exp2f(m - mn);
            m = mn;
            lsum *= al;
#pragma unroll
            for (int r = 0; r < 16; ++r) { oacc[0][r] *= al; oacc[1][r] *= al; }
        }

        float rs0 = 0.f, rs1 = 0.f, rs2 = 0.f, rs3 = 0.f;
#pragma unroll
        for (int kb2 = 0; kb2 < 2; ++kb2)
#pragma unroll
            for (int r = 0; r < 16; ++r) {
                const float p = __builtin_amdgcn_exp2f(sa[kb2][r] - m);
                sa[kb2][r] = p;
                if ((r & 3) == 0) rs0 += p;
                else if ((r & 3) == 1) rs1 += p;
                else if ((r & 3) == 2) rs2 += p;
                else rs3 += p;
            }
        float rs = (rs0 + rs1) + (rs2 + rs3);
        rs += __shfl_xor(rs, 32);
        lsum += rs;

        // ---- pack P^T into B-frags: pb[k4] holds k = 16*k4 + 8*hi + e ----
        // 16 cvt_pk + 8 permlane32_swap (T12):
        // s = plswap(pk[ja][w], pk[jb][w]) -> word[w] = s.x, word[2+w] = s.y
        s16x8 pb[4];
#pragma unroll
        for (int blk = 0; blk < 2; ++blk) {
            u32 pk[4][2];
#pragma unroll
            for (int j = 0; j < 4; ++j) {
                pk[j][0] = cvtpk(sa[blk][4 * j + 0], sa[blk][4 * j + 1]);
                pk[j][1] = cvtpk(sa[blk][4 * j + 2], sa[blk][4 * j + 3]);
            }
#pragma unroll
            for (int halfq = 0; halfq < 2; ++halfq) {
                const int ja = 2 * halfq, jb = ja + 1;
                const i32x2 s0 = plswap(pk[ja][0], pk[jb][0]);
                const i32x2 s1 = plswap(pk[ja][1], pk[jb][1]);
                union { u32 w[4]; s16x8 v; } pu;
                pu.w[0] = (u32)s0.x;   // e0,e1
                pu.w[1] = (u32)s1.x;   // e2,e3
                pu.w[2] = (u32)s0.y;   // e4,e5
                pu.w[3] = (u32)s1.y;   // e6,e7
                pb[blk * 2 + halfq] = pu.v;
            }
        }

        // ---- O^T[d][q] += sum_k V^T[d][k] P^T[k][q] ----
#pragma unroll
        for (int dt = 0; dt < 2; ++dt) {
            const int row = dt * 32 + ri;
#pragma unroll
            for (int k4 = 0; k4 < 4; ++k4) {
                s16x8 vf = *(const s16x8*)(Vsh + row * 72 + (2 * k4 + hi) * 8);
                oacc[dt] = mfma32(vf, pb[k4], oacc[dt]);
            }
        }
    }

    // ---- flash merge of the two KV halves (overlay on staging LDS) ----
    __syncthreads();  // all staging reads done before overlay writes
    if (kvh) {
        float* p = mrg + (wg * 64 + lane) * 35;
        p[0] = m; p[1] = lsum;
#pragma unroll
        for (int r = 0; r < 16; ++r) { p[2 + r] = oacc[0][r]; p[18 + r] = oacc[1][r]; }
    }
    __syncthreads();
    if (!kvh) {
        const float* p = mrg + (wg * 64 + lane) * 35;
        const float m1 = p[0], l1 = p[1];
        const float mn = fmaxf(m, m1);
        const float a0 = __builtin_amdgcn_exp2f(m - mn);
        const float a1 = __builtin_amdgcn_exp2f(m1 - mn);
        const float inv = 1.f / (lsum * a0 + l1 * a1);
        const int t = q0 + ri;
        bf16u* Ob = O + ((size_t)b * 2048 + t) * 1024 + h * 64;
#pragma unroll
        for (int dt = 0; dt < 2; ++dt)
#pragma unroll
            for (int j = 0; j < 4; ++j) {
                const int d0 = dt * 32 + j * 8 + hi * 4;
                const float e0 = (oacc[dt][4 * j + 0] * a0 + p[2 + dt * 16 + 4 * j + 0] * a1) * inv;
                const float e1 = (oacc[dt][4 * j + 1] * a0 + p[2 + dt * 16 + 4 * j + 1] * a1) * inv;
                const float e2 = (oacc[dt][4 * j + 2] * a0 + p[2 + dt * 16 + 4 * j + 2] * a1) * inv;
                const float e3 = (oacc[dt][4 * j + 3] * a0 + p[2 + dt * 16 + 4 * j + 3] * a1) * inv;
                uint2 wv; wv.x = pack2(e0, e1); wv.y = pack2(e2, e3);
                *(uint2*)(Ob + d0) = wv;
            }
    }
}

// ---------- launch ----------
extern "C" void kernel_launch(void* const* d_in, const int* in_sizes, int n_in,
                              void* d_out, int out_size, void* d_ws, size_t ws_size,
                              hipStream_t stream) {
    const float* x     = (const float*)d_in[0];
    const float* w_in  = (const float*)d_in[1];
    const float* b_in  = (const float*)d_in[2];
    const float* w_out = (const float*)d_in[3];
    const float* b_out = (const float*)d_in[4];
    float* out = (float*)d_out;

    char* ws = (char*)d_ws;
    bf16u* xb    = (bf16u*)(ws);                          // 8 MB  (reused as attnb)
    bf16u* wqkvb = (bf16u*)(ws + 8388608);                // 6 MB
    bf16u* woutb = (bf16u*)(ws + 14680064);               // 2 MB
    bf16u* qb    = (bf16u*)(ws + 16777216);               // 8 MB
    bf16u* kb    = (bf16u*)(ws + 25165824);               // 8 MB
    bf16u* vtb   = (bf16u*)(ws + 33554432);               // 8 MB (V stored transposed)
    bf16u* attnb = xb;  // x is dead after the QKV GEMM

    cvt3_f32_bf16_kernel<<<2048, 256, 0, stream>>>(
        x, xb, 4096 * 1024, w_in, wqkvb, 3072 * 1024, w_out, woutb, 1024 * 1024);

    // grid 32x24 = 768 wgs; 768/8 = 96 = 8m x 12n rect per XCD (A 2MB + B 3MB)
    gemm_bt_kernel<1, 8, 12><<<dim3(32, 24), 256, 0, stream>>>(
        xb, wqkvb, b_in, nullptr, qb, kb, vtb, 4096, 3072, 1024);

    attn_kernel<<<dim3(16, 32), 512, 0, stream>>>(qb, kb, vtb, attnb);

    // grid 32x8 = 256 wgs; 256/8 = 32 = 8m x 4n rect per XCD (A 2MB + B 1MB)
    gemm_bt_kernel<0, 8, 4><<<dim3(32, 8), 256, 0, stream>>>(
        attnb, woutb, b_out, out, nullptr, nullptr, nullptr, 4096, 1024, 1024);
}

// Round 11
// 131.969 us; speedup vs baseline: 1.9620x; 1.0139x over previous
//
#include <hip/hip_runtime.h>
#include <stdint.h>

// ---------- types ----------
typedef unsigned short bf16u;                                    // raw bf16 bits
typedef unsigned int u32;
typedef __attribute__((ext_vector_type(8))) short s16x8;         // MFMA A/B frag (8 bf16)
typedef __attribute__((ext_vector_type(4))) float f32x4;         // 16x16 C/D frag
typedef __attribute__((ext_vector_type(16))) float f32x16;       // 32x32 C/D frag
typedef __attribute__((ext_vector_type(2))) int i32x2;

// Q is pre-scaled by 1/sqrt(64) * log2(e) so softmax runs in exp2 domain.
#define QSCALE 0.18033688011112042f

static __device__ __forceinline__ bf16u f2bf(float f) {
    uint32_t u = __float_as_uint(f);
    uint32_t r = (u + 0x7FFFu + ((u >> 16) & 1u)) >> 16;         // RNE
    return (bf16u)r;
}
static __device__ __forceinline__ u32 pack2(float lo, float hi) {
    return (u32)f2bf(lo) | ((u32)f2bf(hi) << 16);
}
// D.lo = bf16(S0), D.hi = bf16(S1), RNE (T12 recipe, m240)
static __device__ __forceinline__ u32 cvtpk(float lo, float hi) {
    u32 r;
    asm("v_cvt_pk_bf16_f32 %0, %1, %2" : "=v"(r) : "v"(lo), "v"(hi));
    return r;
}
// ret.x = X': lanes<32 keep X, lanes>=32 get Y's low half;
// ret.y = Y': lanes<32 get X's high half, lanes>=32 keep Y.
static __device__ __forceinline__ i32x2 plswap(u32 x, u32 y) {
    return __builtin_amdgcn_permlane32_swap((int)x, (int)y, false, false);
}

static __device__ __forceinline__ f32x4 mfma16(s16x8 a, s16x8 b, f32x4 c) {
    return __builtin_amdgcn_mfma_f32_16x16x32_bf16(a, b, c, 0, 0, 0);
}
static __device__ __forceinline__ f32x16 mfma32(s16x8 a, s16x8 b, f32x16 c) {
    return __builtin_amdgcn_mfma_f32_32x32x16_bf16(a, b, c, 0, 0, 0);
}

#define GLDS(gsrc, ldst)                                                        \
    __builtin_amdgcn_global_load_lds(                                           \
        (const __attribute__((address_space(1))) void*)(gsrc),                  \
        (__attribute__((address_space(3))) void*)(ldst), 16, 0, 0)

// ---------- fp32 -> bf16 convert (three arrays fused, one launch) ----------
__global__ __launch_bounds__(256) void cvt3_f32_bf16_kernel(
    const float* __restrict__ in0, bf16u* __restrict__ out0, int n0,
    const float* __restrict__ in1, bf16u* __restrict__ out1, int n1,
    const float* __restrict__ in2, bf16u* __restrict__ out2, int n2) {
    union Pack { bf16u h[8]; uint4 u; };
    const int step = gridDim.x * 256 * 8;
#define CVT_LOOP(inp, outp, n)                                                  \
    for (int i = (blockIdx.x * 256 + threadIdx.x) * 8; i < (n); i += step) {    \
        const float4 a = *(const float4*)((inp) + i);                           \
        const float4 b = *(const float4*)((inp) + i + 4);                       \
        Pack p;                                                                 \
        p.h[0] = f2bf(a.x); p.h[1] = f2bf(a.y); p.h[2] = f2bf(a.z);             \
        p.h[3] = f2bf(a.w); p.h[4] = f2bf(b.x); p.h[5] = f2bf(b.y);             \
        p.h[6] = f2bf(b.z); p.h[7] = f2bf(b.w);                                 \
        *(uint4*)((outp) + i) = p.u;                                            \
    }
    CVT_LOOP(in0, out0, n0)
    CVT_LOOP(in1, out1, n1)
    CVT_LOOP(in2, out2, n2)
#undef CVT_LOOP
}

// ---------- GEMM: C = A @ Bt^T (+bias). A:[M,K] bf16, Bt:[N,K] bf16 ----------
// MODE 0: fp32 out to Cf[M,N].
// MODE 1: scatter bf16: Q (pre-scaled by QSCALE), K -> [BH][2048][64];
//         V -> TRANSPOSED [BH][64][2048].
// XCD swizzle (T1): each XCD owns a RECTM x RECTN rectangle of 128^2 tiles.
// K-loop: single-barrier double-buffer (T3 minimum recipe): issue GLDS for
// tile t+1 into the OTHER buffer, compute tile t, then ONE __syncthreads()
// (its mandatory vmcnt(0) drain lands AFTER compute, so loads overlap MFMA).
// Buffers are distinct static arrays (compile-time parity) to keep alias
// analysis from forcing an early drain.
template <int MODE, int RECTM, int RECTN>
__global__ __launch_bounds__(256) void gemm_bt_kernel(
    const bf16u* __restrict__ A, const bf16u* __restrict__ Bt,
    const float* __restrict__ bias, float* __restrict__ Cf,
    bf16u* __restrict__ Qo, bf16u* __restrict__ Ko, bf16u* __restrict__ Vto,
    int M, int N, int K) {
    __shared__ bf16u As0[128 * 32];  // buffer 0 (linear, global_load_lds dest)
    __shared__ bf16u Bs0[128 * 32];
    __shared__ bf16u As1[128 * 32];  // buffer 1
    __shared__ bf16u Bs1[128 * 32];
    const int tid  = threadIdx.x;
    const int wave = tid >> 6, lane = tid & 63;
    const int wr = wave >> 1, wc = wave & 1;
    const int ri = lane & 15, hi = lane >> 4;

    const int id  = blockIdx.x + blockIdx.y * gridDim.x;  // HW round-robins id%8
    const int xcd = id & 7, rr = id >> 3;                 // rr < RECTM*RECTN
    const int nrm = gridDim.x / RECTM;                    // rect columns in m
    const int m0 = ((xcd % nrm) * RECTM + (rr % RECTM)) * 128;
    const int n0 = ((xcd / nrm) * RECTN + (rr / RECTM)) * 128;

    f32x4 acc[4][4];
#pragma unroll
    for (int i = 0; i < 4; ++i)
#pragma unroll
        for (int j = 0; j < 4; ++j) acc[i][j] = (f32x4){0.f, 0.f, 0.f, 0.f};

// stage K-step (32 wide) starting at k0 into (Ad, Bd)
#define STAGE(Ad, Bd, k0)                                                       \
    _Pragma("unroll")                                                           \
    for (int it = 0; it < 2; ++it) {                                            \
        const int chunk = it * 4 + wave;          /* 0..7, wave-uniform */      \
        const int e = chunk * 512 + lane * 8;                                   \
        const int r = e >> 5, c = e & 31;                                       \
        GLDS(A  + (size_t)(m0 + r) * K + ((k0) + c), (Ad) + chunk * 512);       \
        GLDS(Bt + (size_t)(n0 + r) * K + ((k0) + c), (Bd) + chunk * 512);       \
    }

// compute one K-step from (Asrc, Bsrc)
#define KSTEP(Asrc, Bsrc)                                                       \
    {                                                                           \
        s16x8 af[4], bfr[4];                                                    \
        _Pragma("unroll")                                                       \
        for (int i = 0; i < 4; ++i) {                                           \
            af[i]  = *(const s16x8*)((Asrc) + (wr * 64 + i * 16 + ri) * 32 + hi * 8); \
            bfr[i] = *(const s16x8*)((Bsrc) + (wc * 64 + i * 16 + ri) * 32 + hi * 8); \
        }                                                                       \
        _Pragma("unroll")                                                       \
        for (int i = 0; i < 4; ++i)                                             \
            _Pragma("unroll")                                                   \
            for (int j = 0; j < 4; ++j) acc[i][j] = mfma16(af[i], bfr[j], acc[i][j]); \
    }

    // prologue: stage tile 0 into buffer 0
    STAGE(As0, Bs0, 0)
    __syncthreads();

    const int T = K >> 5;                 // K-steps (K % 64 == 0 for our shapes)
    for (int t2 = 0; t2 < (T >> 1); ++t2) {
        const int t = t2 * 2;
        // even step: stage t+1 -> buf1, compute buf0
        STAGE(As1, Bs1, (t + 1) * 32)
        KSTEP(As0, Bs0)
        __syncthreads();                  // vmcnt(0) drain + barrier (post-compute)
        // odd step: stage t+2 -> buf0 (unless last), compute buf1
        if (t + 2 < T) { STAGE(As0, Bs0, (t + 2) * 32) }
        KSTEP(As1, Bs1)
        __syncthreads();
    }
#undef STAGE
#undef KSTEP

    // epilogue: D layout row=(lane>>4)*4+r, col=lane&15
#pragma unroll
    for (int i = 0; i < 4; ++i) {
#pragma unroll
        for (int j = 0; j < 4; ++j) {
#pragma unroll
            for (int r = 0; r < 4; ++r) {
                const int row = m0 + wr * 64 + i * 16 + hi * 4 + r;
                const int col = n0 + wc * 64 + j * 16 + ri;
                const float v = acc[i][j][r] + bias[col];
                if constexpr (MODE == 0) {
                    Cf[(size_t)row * N + col] = v;
                } else {
                    const int which = col >> 10, h = (col >> 6) & 15, d = col & 63;
                    const int b = row >> 11, t = row & 2047;
                    const int bh = b * 16 + h;
                    if (which == 2) {
                        Vto[(((size_t)bh) * 64 + d) * 2048 + t] = f2bf(v);
                    } else if (which == 0) {
                        Qo[(((size_t)bh) * 2048 + t) * 64 + d] = f2bf(v * QSCALE);
                    } else {
                        Ko[(((size_t)bh) * 2048 + t) * 64 + d] = f2bf(v);
                    }
                }
            }
        }
    }
}

// ---------- flash attention (swapped QK^T, 32x32 MFMA, KV-split) ----------
// Q,K: [BH][2048][64]; Vt: [BH][64][2048]; O: [B][2048][1024] bf16
// Block: 8 waves (512 thr). Wave-groups {0-3}/{4-7}: same 128 q-rows,
// disjoint KV halves (tiles 0-15 / 16-31); flash-merge at the end.
// XCD swizzle: each XCD owns 4 complete bh groups (2 MB KV -> L2-resident).
// LDS rows padded to 72 elems: bank-quad = (row+slot)&7 -> conflict-free.
__global__ __launch_bounds__(512) void attn_kernel(
    const bf16u* __restrict__ Q, const bf16u* __restrict__ K,
    const bf16u* __restrict__ Vt, bf16u* __restrict__ O) {
    __shared__ uint4 smem4[4 * 64 * 72 * 2 / 16];   // 36864 B: 4 staging tiles
    bf16u* Ks0 = (bf16u*)smem4;
    bf16u* Vs0 = Ks0 + 64 * 72;
    bf16u* Ks1 = Vs0 + 64 * 72;
    bf16u* Vs1 = Ks1 + 64 * 72;
    float* mrg = (float*)smem4;                     // overlay after loop: [4][64][35]

    const int tid = threadIdx.x, lane = tid & 63;
    const int wave = tid >> 6, wg = wave & 3, kvh = wave >> 2;
    const int ri = lane & 31, hi = lane >> 5;          // q-col / lane-half

    const int id  = blockIdx.x + blockIdx.y * gridDim.x;  // gridDim.x = 16
    const int xcd = id & 7, rr = id >> 3;                 // rr < 64
    const int bh = xcd * 4 + (rr >> 4);                   // 4 bh groups per XCD
    const int bq = rr & 15;

    const int b = bh >> 4, h = bh & 15;
    const int q0 = bq * 128 + wg * 32;
    const bf16u* Qb = Q  + (size_t)bh * 2048 * 64;
    const bf16u* Kb = K  + (size_t)bh * 2048 * 64;
    const bf16u* Vb = Vt + (size_t)bh * 64 * 2048;

    // Q fragment (B-operand): lane holds row q0+ri, d = 16c + 8hi + e
    s16x8 qf[4];
#pragma unroll
    for (int c = 0; c < 4; ++c)
        qf[c] = *(const s16x8*)(Qb + (size_t)(q0 + ri) * 64 + c * 16 + hi * 8);

    const bf16u* Ksh = kvh ? Ks1 : Ks0;
    const bf16u* Vsh = kvh ? Vs1 : Vs0;

    f32x16 oacc[2];
#pragma unroll
    for (int r = 0; r < 16; ++r) { oacc[0][r] = 0.f; oacc[1][r] = 0.f; }
    float m = -1e30f, lsum = 0.f;

    const int srow = tid >> 3, sc = tid & 7;           // 512 thr: one 16B chunk/tile
    for (int kt = 0; kt < 16; ++kt) {
        // load both halves' tiles to registers (issued before the barrier)
        const uint4 k0 = *(const uint4*)(Kb + (size_t)(kt * 64 + srow) * 64 + sc * 8);
        const uint4 k1 = *(const uint4*)(Kb + (size_t)((kt + 16) * 64 + srow) * 64 + sc * 8);
        const uint4 v0 = *(const uint4*)(Vb + (size_t)srow * 2048 + kt * 64 + sc * 8);
        const uint4 v1 = *(const uint4*)(Vb + (size_t)srow * 2048 + (kt + 16) * 64 + sc * 8);
        __syncthreads();  // previous tile's LDS reads complete
        *(uint4*)(Ks0 + srow * 72 + sc * 8) = k0;
        *(uint4*)(Ks1 + srow * 72 + sc * 8) = k1;
        *(uint4*)(Vs0 + srow * 72 + sc * 8) = v0;
        *(uint4*)(Vs1 + srow * 72 + sc * 8) = v1;
        __syncthreads();

        // S^T[k][q] = sum_d K[k][d] Q[q][d]  (2 tiles of 32k x 32q, 4 mfma each)
        f32x16 sa[2];
#pragma unroll
        for (int r = 0; r < 16; ++r) { sa[0][r] = 0.f; sa[1][r] = 0.f; }
#pragma unroll
        for (int kb2 = 0; kb2 < 2; ++kb2) {
            const int row = kb2 * 32 + ri;
#pragma unroll
            for (int c = 0; c < 4; ++c) {
                s16x8 kf = *(const s16x8*)(Ksh + row * 72 + (2 * c + hi) * 8);
                sa[kb2] = mfma32(kf, qf[c], sa[kb2]);
            }
        }

        // ---- online softmax in exp2 domain (lane owns q = q0+ri) ----
        float pmt[16];
#pragma unroll
        for (int r = 0; r < 16; ++r) pmt[r] = fmaxf(sa[0][r], sa[1][r]);
#pragma unroll
        for (int s = 8; s > 0; s >>= 1)
#pragma unroll
            for (int r = 0; r < s; ++r) pmt[r] = fmaxf(pmt[r], pmt[r + s]);
        const float pm = fmaxf(pmt[0], __shfl_xor(pmt[0], 32));

        // defer-max (T13): only rescale when the running max grows by > 8
        if (!__all(pm <= m + 8.f)) {
            const float mn = fmaxf(m, pm);
            const float al = __builtin_amdgcn_exp2f(m - mn);
            m = mn;
            lsum *= al;
#pragma unroll
            for (int r = 0; r < 16; ++r) { oacc[0][r] *= al; oacc[1][r] *= al; }
        }

        float rs0 = 0.f, rs1 = 0.f, rs2 = 0.f, rs3 = 0.f;
#pragma unroll
        for (int kb2 = 0; kb2 < 2; ++kb2)
#pragma unroll
            for (int r = 0; r < 16; ++r) {
                const float p = __builtin_amdgcn_exp2f(sa[kb2][r] - m);
                sa[kb2][r] = p;
                if ((r & 3) == 0) rs0 += p;
                else if ((r & 3) == 1) rs1 += p;
                else if ((r & 3) == 2) rs2 += p;
                else rs3 += p;
            }
        float rs = (rs0 + rs1) + (rs2 + rs3);
        rs += __shfl_xor(rs, 32);
        lsum += rs;

        // ---- pack P^T into B-frags: pb[k4] holds k = 16*k4 + 8*hi + e ----
        // 16 cvt_pk + 8 permlane32_swap (T12):
        // s = plswap(pk[ja][w], pk[jb][w]) -> word[w] = s.x, word[2+w] = s.y
        s16x8 pb[4];
#pragma unroll
        for (int blk = 0; blk < 2; ++blk) {
            u32 pk[4][2];
#pragma unroll
            for (int j = 0; j < 4; ++j) {
                pk[j][0] = cvtpk(sa[blk][4 * j + 0], sa[blk][4 * j + 1]);
                pk[j][1] = cvtpk(sa[blk][4 * j + 2], sa[blk][4 * j + 3]);
            }
#pragma unroll
            for (int halfq = 0; halfq < 2; ++halfq) {
                const int ja = 2 * halfq, jb = ja + 1;
                const i32x2 s0 = plswap(pk[ja][0], pk[jb][0]);
                const i32x2 s1 = plswap(pk[ja][1], pk[jb][1]);
                union { u32 w[4]; s16x8 v; } pu;
                pu.w[0] = (u32)s0.x;   // e0,e1
                pu.w[1] = (u32)s1.x;   // e2,e3
                pu.w[2] = (u32)s0.y;   // e4,e5
                pu.w[3] = (u32)s1.y;   // e6,e7
                pb[blk * 2 + halfq] = pu.v;
            }
        }

        // ---- O^T[d][q] += sum_k V^T[d][k] P^T[k][q] ----
#pragma unroll
        for (int dt = 0; dt < 2; ++dt) {
            const int row = dt * 32 + ri;
#pragma unroll
            for (int k4 = 0; k4 < 4; ++k4) {
                s16x8 vf = *(const s16x8*)(Vsh + row * 72 + (2 * k4 + hi) * 8);
                oacc[dt] = mfma32(vf, pb[k4], oacc[dt]);
            }
        }
    }

    // ---- flash merge of the two KV halves (overlay on staging LDS) ----
    __syncthreads();  // all staging reads done before overlay writes
    if (kvh) {
        float* p = mrg + (wg * 64 + lane) * 35;
        p[0] = m; p[1] = lsum;
#pragma unroll
        for (int r = 0; r < 16; ++r) { p[2 + r] = oacc[0][r]; p[18 + r] = oacc[1][r]; }
    }
    __syncthreads();
    if (!kvh) {
        const float* p = mrg + (wg * 64 + lane) * 35;
        const float m1 = p[0], l1 = p[1];
        const float mn = fmaxf(m, m1);
        const float a0 = __builtin_amdgcn_exp2f(m - mn);
        const float a1 = __builtin_amdgcn_exp2f(m1 - mn);
        const float inv = 1.f / (lsum * a0 + l1 * a1);
        const int t = q0 + ri;
        bf16u* Ob = O + ((size_t)b * 2048 + t) * 1024 + h * 64;
#pragma unroll
        for (int dt = 0; dt < 2; ++dt)
#pragma unroll
            for (int j = 0; j < 4; ++j) {
                const int d0 = dt * 32 + j * 8 + hi * 4;
                const float e0 = (oacc[dt][4 * j + 0] * a0 + p[2 + dt * 16 + 4 * j + 0] * a1) * inv;
                const float e1 = (oacc[dt][4 * j + 1] * a0 + p[2 + dt * 16 + 4 * j + 1] * a1) * inv;
                const float e2 = (oacc[dt][4 * j + 2] * a0 + p[2 + dt * 16 + 4 * j + 2] * a1) * inv;
                const float e3 = (oacc[dt][4 * j + 3] * a0 + p[2 + dt * 16 + 4 * j + 3] * a1) * inv;
                uint2 wv; wv.x = pack2(e0, e1); wv.y = pack2(e2, e3);
                *(uint2*)(Ob + d0) = wv;
            }
    }
}

// ---------- launch ----------
extern "C" void kernel_launch(void* const* d_in, const int* in_sizes, int n_in,
                              void* d_out, int out_size, void* d_ws, size_t ws_size,
                              hipStream_t stream) {
    const float* x     = (const float*)d_in[0];
    const float* w_in  = (const float*)d_in[1];
    const float* b_in  = (const float*)d_in[2];
    const float* w_out = (const float*)d_in[3];
    const float* b_out = (const float*)d_in[4];
    float* out = (float*)d_out;

    char* ws = (char*)d_ws;
    bf16u* xb    = (bf16u*)(ws);                          // 8 MB  (reused as attnb)
    bf16u* wqkvb = (bf16u*)(ws + 8388608);                // 6 MB
    bf16u* woutb = (bf16u*)(ws + 14680064);               // 2 MB
    bf16u* qb    = (bf16u*)(ws + 16777216);               // 8 MB
    bf16u* kb    = (bf16u*)(ws + 25165824);               // 8 MB
    bf16u* vtb   = (bf16u*)(ws + 33554432);               // 8 MB (V stored transposed)
    bf16u* attnb = xb;  // x is dead after the QKV GEMM

    cvt3_f32_bf16_kernel<<<2048, 256, 0, stream>>>(
        x, xb, 4096 * 1024, w_in, wqkvb, 3072 * 1024, w_out, woutb, 1024 * 1024);

    // grid 32x24 = 768 wgs; 768/8 = 96 = 8m x 12n rect per XCD (A 2MB + B 3MB)
    gemm_bt_kernel<1, 8, 12><<<dim3(32, 24), 256, 0, stream>>>(
        xb, wqkvb, b_in, nullptr, qb, kb, vtb, 4096, 3072, 1024);

    attn_kernel<<<dim3(16, 32), 512, 0, stream>>>(qb, kb, vtb, attnb);

    // grid 32x8 = 256 wgs; 256/8 = 32 = 8m x 4n rect per XCD (A 2MB + B 1MB)
    gemm_bt_kernel<0, 8, 4><<<dim3(32, 8), 256, 0, stream>>>(
        attnb, woutb, b_out, out, nullptr, nullptr, nullptr, 4096, 1024, 1024);
}